// Round 12
// baseline (932.807 us; speedup 1.0000x reference)
//
#include <hip/hip_runtime.h>
#include <hip/hip_fp16.h>

#define NEG_SLOPE 0.2f
#define CH 4096        // edges per partition chunk
#define UN 16          // CH / 256
#define BW 512         // dst nodes per partition bucket (bucket = dst >> 9)
#define CAP2 10240     // padded per-bucket capacity (mean 8704, sigma~93: +16 sigma, guarded)
#define QCAP 2560      // per-quarter keep-list capacity (mean 2176, sigma~47: +8 sigma, guarded)

// ---------------------------------------------------------------------------
// Register-blocked GEMM: x[N,64] @ (Wl||Wr)[64,128] -> xl,xr [N,64] in fp16.
// Block 0 also zeroes bcount (runs before k_part in-stream; saves a dispatch).
// ---------------------------------------------------------------------------
__global__ __launch_bounds__(256) void k_gemm(const float* __restrict__ x,
                                              const float* __restrict__ Wl,
                                              const float* __restrict__ Wr,
                                              __half* __restrict__ xl,
                                              __half* __restrict__ xr,
                                              int* __restrict__ bcount,
                                              int NB, int N) {
    __shared__ float sX[128 * 64];   // 32 KB
    __shared__ float sW[64 * 128];   // 32 KB
    const int t = threadIdx.x;
    const int B = blockIdx.x * 128;

    if (blockIdx.x == 0 && t < NB) bcount[t] = 0;

    for (int f = t; f < 2048; f += 256) {
        const int k = f >> 5, cg = f & 31;
        float4 v;
        if (cg < 16) v = reinterpret_cast<const float4*>(Wl)[k * 16 + cg];
        else         v = reinterpret_cast<const float4*>(Wr)[k * 16 + (cg - 16)];
        reinterpret_cast<float4*>(sW)[f] = v;
    }
    for (int f = t; f < 2048; f += 256) {
        const int r = B + (f >> 4);
        float4 v = {0.f, 0.f, 0.f, 0.f};
        if (r < N) v = reinterpret_cast<const float4*>(x)[(size_t)B * 16 + f];
        reinterpret_cast<float4*>(sX)[f] = v;
    }
    __syncthreads();

    const int cg = t & 31;
    const int g  = t >> 5;

    float4 acc[16];
#pragma unroll
    for (int i = 0; i < 16; i++) acc[i] = make_float4(0.f, 0.f, 0.f, 0.f);

    for (int kk = 0; kk < 64; kk += 4) {
        const float4 w0 = reinterpret_cast<const float4*>(sW)[(kk + 0) * 32 + cg];
        const float4 w1 = reinterpret_cast<const float4*>(sW)[(kk + 1) * 32 + cg];
        const float4 w2 = reinterpret_cast<const float4*>(sW)[(kk + 2) * 32 + cg];
        const float4 w3 = reinterpret_cast<const float4*>(sW)[(kk + 3) * 32 + cg];
#pragma unroll
        for (int i = 0; i < 16; i++) {
            const float4 xv = reinterpret_cast<const float4*>(sX)[(g * 16 + i) * 16 + (kk >> 2)];
            acc[i].x = fmaf(xv.x, w0.x, acc[i].x);
            acc[i].y = fmaf(xv.x, w0.y, acc[i].y);
            acc[i].z = fmaf(xv.x, w0.z, acc[i].z);
            acc[i].w = fmaf(xv.x, w0.w, acc[i].w);
            acc[i].x = fmaf(xv.y, w1.x, acc[i].x);
            acc[i].y = fmaf(xv.y, w1.y, acc[i].y);
            acc[i].z = fmaf(xv.y, w1.z, acc[i].z);
            acc[i].w = fmaf(xv.y, w1.w, acc[i].w);
            acc[i].x = fmaf(xv.z, w2.x, acc[i].x);
            acc[i].y = fmaf(xv.z, w2.y, acc[i].y);
            acc[i].z = fmaf(xv.z, w2.z, acc[i].z);
            acc[i].w = fmaf(xv.z, w2.w, acc[i].w);
            acc[i].x = fmaf(xv.w, w3.x, acc[i].x);
            acc[i].y = fmaf(xv.w, w3.y, acc[i].y);
            acc[i].z = fmaf(xv.w, w3.z, acc[i].z);
            acc[i].w = fmaf(xv.w, w3.w, acc[i].w);
        }
    }

    const int c = cg * 4;
    __half* dstp = (c < 64) ? (xl + c) : (xr + (c - 64));
#pragma unroll
    for (int i = 0; i < 16; i++) {
        const int r = B + g * 16 + i;
        if (r < N) {
            __half2 h01, h23;
            h01.x = __float2half_rn(acc[i].x);
            h01.y = __float2half_rn(acc[i].y);
            h23.x = __float2half_rn(acc[i].z);
            h23.y = __float2half_rn(acc[i].w);
            uint2 u;
            u.x = *reinterpret_cast<unsigned int*>(&h01);
            u.y = *reinterpret_cast<unsigned int*>(&h23);
            *reinterpret_cast<uint2*>(dstp + (size_t)r * 64) = u;
        }
    }
}

// ---------------------------------------------------------------------------
// Histogram + partition into padded 512-node buckets (stride CAP2).
// LDS-staged: histogram -> scan -> global run reservation -> bucket-sorted
// placement in LDS -> sequential writeout (contiguous runs).
// ---------------------------------------------------------------------------
__global__ __launch_bounds__(256) void k_part(const int* __restrict__ src,
                                              const int* __restrict__ dst,
                                              int* __restrict__ bcount,
                                              int* __restrict__ part,
                                              int E, int M, int NB) {
    __shared__ int skey[CH];             // 16 KB
    __shared__ unsigned char sbkt[CH];   // 4 KB
    __shared__ int hist[256];
    __shared__ int lcur[256];
    __shared__ int gofs[256];
    const int t = threadIdx.x;
    const int b = blockIdx.x;
    const int lo = b * CH;
    const int cnt = min(M - lo, CH);

    hist[t] = 0;
    __syncthreads();

    int rs[UN], rd[UN];
#pragma unroll
    for (int u = 0; u < UN; u++) {
        const int k = lo + t + u * 256;
        rd[u] = -1; rs[u] = 0;
        if (k < M) {
            if (k < E) { rs[u] = src[k]; rd[u] = dst[k]; }
            else       { rs[u] = k - E;  rd[u] = rs[u]; }
        }
    }
#pragma unroll
    for (int u = 0; u < UN; u++)
        if (rd[u] >= 0) atomicAdd(&hist[rd[u] >> 9], 1);
    __syncthreads();

    // exclusive scan of hist[256] (Hillis-Steele)
    const int h = hist[t];
    lcur[t] = h;
    __syncthreads();
    for (int o = 1; o < 256; o <<= 1) {
        const int v = (t >= o) ? lcur[t - o] : 0;
        __syncthreads();
        lcur[t] += v;
        __syncthreads();
    }
    const int ex = lcur[t] - h;
    int gbase = 0;
    if (t < NB && h > 0) gbase = atomicAdd(&bcount[t], h);
    __syncthreads();
    lcur[t] = ex;                      // local cursor
    gofs[t] = t * CAP2 + gbase - ex;   // LDS slot i of bucket t -> global gofs[t]+i
    __syncthreads();

#pragma unroll
    for (int u = 0; u < UN; u++) {
        if (rd[u] >= 0) {
            const int bkt = rd[u] >> 9;
            const int p = atomicAdd(&lcur[bkt], 1);
            skey[p] = (rs[u] << 9) | (rd[u] & 511);
            sbkt[p] = (unsigned char)bkt;
        }
    }
    __syncthreads();

    for (int i = t; i < cnt; i += 256) {
        const int bkt = sbkt[i];
        const int pos = gofs[bkt] + i;
        if (pos - bkt * CAP2 < CAP2) part[pos] = skey[i];
    }
}

// ---------------------------------------------------------------------------
// Sort-free fused GATv2. 4 blocks per 512-bucket; each owns a 128-node
// quarter: (a) wave-ballot compaction of the quarter's keys from part,
// (b) edge-parallel 16-lane groups: gather xl, dot+shfl+exp, LDS fp32
// atomic accumulation (group-rotated element order -> 2-way banks),
// (c) coalesced float4 finalize out = acc/s + bias.
// No max-subtraction (softmax shift-invariant; logits O(8)).
// ---------------------------------------------------------------------------
__global__ __launch_bounds__(256) void k_fused2(const int* __restrict__ part,
                                                const int* __restrict__ bcount,
                                                const __half* __restrict__ xl,
                                                const __half* __restrict__ xr,
                                                const float* __restrict__ att,
                                                const float* __restrict__ bias,
                                                float* __restrict__ out, int N) {
    __shared__ float acc[128 * 64];  // 32 KB
    __shared__ float sden[128];
    __shared__ int keep[QCAP];       // 10 KB
    __shared__ int kcnt;
    const int t = threadIdx.x;
    const int bkt = blockIdx.x >> 2;
    const int qt  = blockIdx.x & 3;
    const int base = bkt * CAP2;
    const int n = min(bcount[bkt], CAP2);

    for (int i = t; i < 8192; i += 256) acc[i] = 0.f;
    if (t < 128) sden[t] = 0.f;
    if (t == 0) kcnt = 0;
    __syncthreads();

    // (a) compaction: one atomic per wave via ballot
    const int lane = t & 63;
    const int rounds = (n + 255) >> 8;
    for (int r = 0; r < rounds; ++r) {
        const int i = (r << 8) + t;
        int k = 0;
        bool m = false;
        if (i < n) {
            k = part[base + i];
            m = (((k >> 7) & 3) == qt);
        }
        const unsigned long long bal = __ballot(m);
        if (bal) {
            const int leader = __ffsll(bal) - 1;
            int b2 = 0;
            if (lane == leader) b2 = atomicAdd(&kcnt, __popcll(bal));
            b2 = __shfl(b2, leader);
            if (m) {
                const int off = __popcll(bal & ((1ull << lane) - 1));
                const int p = b2 + off;
                if (p < QCAP) keep[p] = k;
            }
        }
    }
    __syncthreads();
    const int ne = min(kcnt, QCAP);

    // (b) edge-parallel accumulate
    const int grp = t >> 4;        // 16 groups per block
    const int gl  = t & 15;
    const int gw  = grp & 3;       // group index within wave (bank decorrelation)
    const float4 a = reinterpret_cast<const float4*>(att)[gl];
    for (int e = grp; e < ne; e += 16) {
        const int k = keep[e];
        const int src = k >> 9;
        const int dlo = k & 127;
        const int gnode = (bkt << 9) + (qt << 7) + dlo;
        const uint2 xu = reinterpret_cast<const uint2*>(xl + (size_t)src * 64)[gl];
        const uint2 ru = reinterpret_cast<const uint2*>(xr + (size_t)gnode * 64)[gl];
        const float2 l01 = __half22float2(*reinterpret_cast<const __half2*>(&xu.x));
        const float2 l23 = __half22float2(*reinterpret_cast<const __half2*>(&xu.y));
        const float2 r01 = __half22float2(*reinterpret_cast<const __half2*>(&ru.x));
        const float2 r23 = __half22float2(*reinterpret_cast<const __half2*>(&ru.y));
        float lv[4] = {l01.x, l01.y, l23.x, l23.y};
        float v0 = lv[0] + r01.x; v0 = fmaxf(v0, NEG_SLOPE * v0);
        float v1 = lv[1] + r01.y; v1 = fmaxf(v1, NEG_SLOPE * v1);
        float v2 = lv[2] + r23.x; v2 = fmaxf(v2, NEG_SLOPE * v2);
        float v3 = lv[3] + r23.y; v3 = fmaxf(v3, NEG_SLOPE * v3);
        float p = a.x * v0 + a.y * v1 + a.z * v2 + a.w * v3;
        p += __shfl_xor(p, 1, 16);
        p += __shfl_xor(p, 2, 16);
        p += __shfl_xor(p, 4, 16);
        p += __shfl_xor(p, 8, 16);
        const float w = __expf(p);
        if (gl == 0) atomicAdd(&sden[dlo], w);
        float* ap = &acc[dlo * 64 + gl * 4];
#pragma unroll
        for (int j = 0; j < 4; j++) {
            const int jj = (j + gw) & 3;
            atomicAdd(ap + jj, w * lv[jj]);
        }
    }
    __syncthreads();

    // (c) finalize: 128 nodes x 16 float4
    for (int i = t; i < 2048; i += 256) {
        const int nl = i >> 4, c = i & 15;
        const int gnode = (bkt << 9) + (qt << 7) + nl;
        if (gnode < N) {
            const float inv = 1.f / sden[nl];
            const float4 bb = reinterpret_cast<const float4*>(bias)[c];
            const float* ap = &acc[nl * 64 + c * 4];
            float4 o;
            o.x = fmaf(ap[0], inv, bb.x);
            o.y = fmaf(ap[1], inv, bb.y);
            o.z = fmaf(ap[2], inv, bb.z);
            o.w = fmaf(ap[3], inv, bb.w);
            reinterpret_cast<float4*>(out)[(size_t)gnode * 16 + c] = o;
        }
    }
}

extern "C" void kernel_launch(void* const* d_in, const int* in_sizes, int n_in,
                              void* d_out, int out_size, void* d_ws, size_t ws_size,
                              hipStream_t stream) {
    const float* x    = (const float*)d_in[0];
    const int*   ei   = (const int*)d_in[1];   // [2,E] (int32 view)
    const float* Wl   = (const float*)d_in[2];
    const float* Wr   = (const float*)d_in[3];
    const float* att  = (const float*)d_in[4];
    const float* bias = (const float*)d_in[5];
    float* out = (float*)d_out;

    const int N = in_sizes[0] / 64;
    const int E = in_sizes[1] / 2;
    const int M = E + N;
    const int ng  = (N + 127) / 128;        // gemm tiles
    const int nch = (M + CH - 1) / CH;      // partition chunks (416)
    const int NB  = (N + BW - 1) / BW;      // buckets (196)

    // workspace: xl[N*64] h | xr[N*64] h | bcount[NB] | part[NB*CAP2]
    __half* xl = (__half*)d_ws;
    __half* xr = xl + (size_t)N * 64;
    int* bcount = (int*)(xr + (size_t)N * 64);
    int* part   = bcount + NB;

    k_gemm<<<ng, 256, 0, stream>>>(x, Wl, Wr, xl, xr, bcount, NB, N);
    k_part<<<nch, 256, 0, stream>>>(ei, ei + E, bcount, part, E, M, NB);
    k_fused2<<<NB * 4, 256, 0, stream>>>(part, bcount, xl, xr, att, bias, out, N);
}

// Round 14
// 197.976 us; speedup vs baseline: 4.7117x; 4.7117x over previous
//
#include <hip/hip_runtime.h>
#include <hip/hip_fp16.h>

#define NEG_SLOPE 0.2f
#define CH 4096        // edges per partition chunk
#define UN 16          // CH / 256
#define BW 512         // dst nodes per partition bucket (bucket = dst >> 9)
#define CAP2 10240     // padded per-bucket capacity (mean 8704, sigma~93: +16 sigma, guarded)
#define QCAP 2560      // per-quarter capacity (mean 2176, sigma~47: +8 sigma, guarded)

// ---------------------------------------------------------------------------
// Fused GEMM + partition (independent work, one dispatch).
// Blocks [0,ng): register-blocked GEMM x[N,64]@(Wl||Wr) -> xl,xr fp16.
// Blocks [ng,ng+nch): histogram+partition of edges into padded 512-node
// buckets (LDS-staged, contiguous run writeout).
// ---------------------------------------------------------------------------
__global__ __launch_bounds__(256) void k_gp(const float* __restrict__ x,
                                            const float* __restrict__ Wl,
                                            const float* __restrict__ Wr,
                                            __half* __restrict__ xl,
                                            __half* __restrict__ xr,
                                            const int* __restrict__ src,
                                            const int* __restrict__ dst,
                                            int* __restrict__ bcount,
                                            int* __restrict__ part,
                                            int E, int M, int NB, int ng, int N) {
    __shared__ float smem[16384];  // 64 KB, unioned between roles
    const int t = threadIdx.x;

    if (blockIdx.x < ng) {
        // ---------------- GEMM role ----------------
        float* sX = smem;          // [128][64]
        float* sW = smem + 8192;   // [64][128]
        const int B = blockIdx.x * 128;

        for (int f = t; f < 2048; f += 256) {
            const int k = f >> 5, cg = f & 31;
            float4 v;
            if (cg < 16) v = reinterpret_cast<const float4*>(Wl)[k * 16 + cg];
            else         v = reinterpret_cast<const float4*>(Wr)[k * 16 + (cg - 16)];
            reinterpret_cast<float4*>(sW)[f] = v;
        }
        for (int f = t; f < 2048; f += 256) {
            const int r = B + (f >> 4);
            float4 v = {0.f, 0.f, 0.f, 0.f};
            if (r < N) v = reinterpret_cast<const float4*>(x)[(size_t)B * 16 + f];
            reinterpret_cast<float4*>(sX)[f] = v;
        }
        __syncthreads();

        const int cg = t & 31;
        const int g  = t >> 5;

        float4 acc[16];
#pragma unroll
        for (int i = 0; i < 16; i++) acc[i] = make_float4(0.f, 0.f, 0.f, 0.f);

        for (int kk = 0; kk < 64; kk += 4) {
            const float4 w0 = reinterpret_cast<const float4*>(sW)[(kk + 0) * 32 + cg];
            const float4 w1 = reinterpret_cast<const float4*>(sW)[(kk + 1) * 32 + cg];
            const float4 w2 = reinterpret_cast<const float4*>(sW)[(kk + 2) * 32 + cg];
            const float4 w3 = reinterpret_cast<const float4*>(sW)[(kk + 3) * 32 + cg];
#pragma unroll
            for (int i = 0; i < 16; i++) {
                const float4 xv = reinterpret_cast<const float4*>(sX)[(g * 16 + i) * 16 + (kk >> 2)];
                acc[i].x = fmaf(xv.x, w0.x, acc[i].x);
                acc[i].y = fmaf(xv.x, w0.y, acc[i].y);
                acc[i].z = fmaf(xv.x, w0.z, acc[i].z);
                acc[i].w = fmaf(xv.x, w0.w, acc[i].w);
                acc[i].x = fmaf(xv.y, w1.x, acc[i].x);
                acc[i].y = fmaf(xv.y, w1.y, acc[i].y);
                acc[i].z = fmaf(xv.y, w1.z, acc[i].z);
                acc[i].w = fmaf(xv.y, w1.w, acc[i].w);
                acc[i].x = fmaf(xv.z, w2.x, acc[i].x);
                acc[i].y = fmaf(xv.z, w2.y, acc[i].y);
                acc[i].z = fmaf(xv.z, w2.z, acc[i].z);
                acc[i].w = fmaf(xv.z, w2.w, acc[i].w);
                acc[i].x = fmaf(xv.w, w3.x, acc[i].x);
                acc[i].y = fmaf(xv.w, w3.y, acc[i].y);
                acc[i].z = fmaf(xv.w, w3.z, acc[i].z);
                acc[i].w = fmaf(xv.w, w3.w, acc[i].w);
            }
        }

        const int c = cg * 4;
        __half* dstp = (c < 64) ? (xl + c) : (xr + (c - 64));
#pragma unroll
        for (int i = 0; i < 16; i++) {
            const int r = B + g * 16 + i;
            if (r < N) {
                __half2 h01, h23;
                h01.x = __float2half_rn(acc[i].x);
                h01.y = __float2half_rn(acc[i].y);
                h23.x = __float2half_rn(acc[i].z);
                h23.y = __float2half_rn(acc[i].w);
                uint2 u;
                u.x = *reinterpret_cast<unsigned int*>(&h01);
                u.y = *reinterpret_cast<unsigned int*>(&h23);
                *reinterpret_cast<uint2*>(dstp + (size_t)r * 64) = u;
            }
        }
    } else {
        // ---------------- partition role ----------------
        int* skey = (int*)smem;                              // [CH] 16 KB
        unsigned char* sbkt = (unsigned char*)(smem + 4096); // [CH] 4 KB
        int* hist = (int*)smem + 5120;                       // [256]
        int* lcur = (int*)smem + 5376;                       // [256]
        int* gofs = (int*)smem + 5632;                       // [256]
        const int b = blockIdx.x - ng;
        const int lo = b * CH;
        const int cnt = min(M - lo, CH);

        hist[t] = 0;
        __syncthreads();

        int rs[UN], rd[UN];
#pragma unroll
        for (int u = 0; u < UN; u++) {
            const int k = lo + t + u * 256;
            rd[u] = -1; rs[u] = 0;
            if (k < M) {
                if (k < E) { rs[u] = src[k]; rd[u] = dst[k]; }
                else       { rs[u] = k - E;  rd[u] = rs[u]; }
            }
        }
#pragma unroll
        for (int u = 0; u < UN; u++)
            if (rd[u] >= 0) atomicAdd(&hist[rd[u] >> 9], 1);
        __syncthreads();

        // exclusive scan of hist[256] (Hillis-Steele)
        const int h = hist[t];
        lcur[t] = h;
        __syncthreads();
        for (int o = 1; o < 256; o <<= 1) {
            const int v = (t >= o) ? lcur[t - o] : 0;
            __syncthreads();
            lcur[t] += v;
            __syncthreads();
        }
        const int ex = lcur[t] - h;
        int gbase = 0;
        if (t < NB && h > 0) gbase = atomicAdd(&bcount[t], h);
        __syncthreads();
        lcur[t] = ex;
        gofs[t] = t * CAP2 + gbase - ex;
        __syncthreads();

#pragma unroll
        for (int u = 0; u < UN; u++) {
            if (rd[u] >= 0) {
                const int bkt = rd[u] >> 9;
                const int p = atomicAdd(&lcur[bkt], 1);
                skey[p] = (rs[u] << 9) | (rd[u] & 511);
                sbkt[p] = (unsigned char)bkt;
            }
        }
        __syncthreads();

        for (int i = t; i < cnt; i += 256) {
            const int bkt = sbkt[i];
            const int pos = gofs[bkt] + i;
            if (pos - bkt * CAP2 < CAP2) part[pos] = skey[i];
        }
    }
}

// ---------------------------------------------------------------------------
// Sort, filtered: 4 blocks per 512-bucket, each owns a 128-node quarter.
// Ballot-compacts its quarter's keys from part (one LDS atomic per wave per
// round), counting-sorts 128 local dsts in LDS, writes sedge coalesced into
// the quarter's padded region. Emits off/deg pointing there.
// ---------------------------------------------------------------------------
__global__ __launch_bounds__(256) void k_bsf(const int* __restrict__ part,
                                             const int* __restrict__ bcount,
                                             int* __restrict__ sedge,
                                             int* __restrict__ off,
                                             int* __restrict__ deg, int N) {
    __shared__ int skey[QCAP];   // 10 KB
    __shared__ int outk[QCAP];   // 10 KB
    __shared__ int lhist[128];
    __shared__ int loff[128];
    __shared__ int lcur[128];
    __shared__ int sh2[128];
    __shared__ int kcnt;
    const int t = threadIdx.x;
    const int lane = t & 63;
    const int bkt = blockIdx.x >> 2;
    const int qt  = blockIdx.x & 3;
    const int base  = bkt * CAP2;
    const int qbase = base + qt * QCAP;
    const int n = min(bcount[bkt], CAP2);

    if (t == 0) kcnt = 0;
    if (t < 128) lhist[t] = 0;
    __syncthreads();

    // ballot compaction: one kcnt atomic per wave per round
    const int rounds = (n + 255) >> 8;
    for (int r = 0; r < rounds; ++r) {
        const int i = (r << 8) + t;
        int k = 0;
        bool m = false;
        if (i < n) {
            k = part[base + i];
            m = (((k >> 7) & 3) == qt);
        }
        const unsigned long long bal = __ballot(m);
        if (bal) {
            const int leader = __ffsll(bal) - 1;
            int b2 = 0;
            if (lane == leader) b2 = atomicAdd(&kcnt, __popcll(bal));
            b2 = __shfl(b2, leader);
            if (m) {
                const int p = b2 + __popcll(bal & ((1ull << lane) - 1));
                if (p < QCAP) {
                    skey[p] = k;
                    atomicAdd(&lhist[k & 127], 1);
                }
            }
        }
    }
    __syncthreads();
    const int m = min(kcnt, QCAP);

    // exclusive scan of lhist[128] (threads 0..127)
    if (t < 128) sh2[t] = lhist[t];
    __syncthreads();
    for (int o = 1; o < 128; o <<= 1) {
        int v = 0;
        if (t < 128 && t >= o) v = sh2[t - o];
        __syncthreads();
        if (t < 128) sh2[t] += v;
        __syncthreads();
    }
    if (t < 128) {
        const int ex = sh2[t] - lhist[t];
        loff[t] = ex;
        lcur[t] = ex;
        const int node = (bkt << 9) + (qt << 7) + t;
        if (node < N) { off[node] = qbase + ex; deg[node] = lhist[t]; }
    }
    __syncthreads();

    for (int i = t; i < m; i += 256) {
        const int k = skey[i];
        const int pos = atomicAdd(&lcur[k & 127], 1);
        outk[pos] = k >> 9;
    }
    __syncthreads();
    for (int i = t; i < m; i += 256) sedge[qbase + i] = outk[i];
}

// ---------------------------------------------------------------------------
// fused per-node GATv2: one wave per dst node, 16 lanes x 4 edge groups,
// 2-deep edge unroll for gather ILP, fp16 xl/xr. No max-subtraction
// (softmax shift-invariant; logits O(8) -> exp safe in fp32).
// ---------------------------------------------------------------------------
__global__ void k_fused(const int* __restrict__ offv, const int* __restrict__ degv,
                        const int* __restrict__ sedge, const __half* __restrict__ xl,
                        const __half* __restrict__ xr, const float* __restrict__ att,
                        const float* __restrict__ bias, float* __restrict__ out, int N) {
    const int lane = threadIdx.x & 63;
    const int gl = lane & 15;   // lane within edge-group (dim/4)
    const int q = lane >> 4;    // edge-group 0..3
    int wave = (blockIdx.x * blockDim.x + threadIdx.x) >> 6;
    const int nw = (gridDim.x * blockDim.x) >> 6;
    const float4 a = reinterpret_cast<const float4*>(att)[gl];
    const float4 b = reinterpret_cast<const float4*>(bias)[gl];
    for (int i = wave; i < N; i += nw) {
        const int base = offv[i];
        const int dg = degv[i];
        const uint2 xru = reinterpret_cast<const uint2*>(xr + (size_t)i * 64)[gl];
        const float2 r01 = __half22float2(*reinterpret_cast<const __half2*>(&xru.x));
        const float2 r23 = __half22float2(*reinterpret_cast<const __half2*>(&xru.y));
        float s = 0.f;
        float4 acc = {0.f, 0.f, 0.f, 0.f};
        int tt = q;
        for (; tt + 4 < dg; tt += 8) {
            const int j0 = sedge[base + tt];
            const int j1 = sedge[base + tt + 4];
            const uint2 xu0 = reinterpret_cast<const uint2*>(xl + (size_t)j0 * 64)[gl];
            const uint2 xu1 = reinterpret_cast<const uint2*>(xl + (size_t)j1 * 64)[gl];
            const float2 l01a = __half22float2(*reinterpret_cast<const __half2*>(&xu0.x));
            const float2 l23a = __half22float2(*reinterpret_cast<const __half2*>(&xu0.y));
            const float2 l01b = __half22float2(*reinterpret_cast<const __half2*>(&xu1.x));
            const float2 l23b = __half22float2(*reinterpret_cast<const __half2*>(&xu1.y));
            float v0 = l01a.x + r01.x; v0 = fmaxf(v0, NEG_SLOPE * v0);
            float v1 = l01a.y + r01.y; v1 = fmaxf(v1, NEG_SLOPE * v1);
            float v2 = l23a.x + r23.x; v2 = fmaxf(v2, NEG_SLOPE * v2);
            float v3 = l23a.y + r23.y; v3 = fmaxf(v3, NEG_SLOPE * v3);
            float u0 = l01b.x + r01.x; u0 = fmaxf(u0, NEG_SLOPE * u0);
            float u1 = l01b.y + r01.y; u1 = fmaxf(u1, NEG_SLOPE * u1);
            float u2 = l23b.x + r23.x; u2 = fmaxf(u2, NEG_SLOPE * u2);
            float u3 = l23b.y + r23.y; u3 = fmaxf(u3, NEG_SLOPE * u3);
            float p0 = a.x * v0 + a.y * v1 + a.z * v2 + a.w * v3;
            float p1 = a.x * u0 + a.y * u1 + a.z * u2 + a.w * u3;
            p0 += __shfl_xor(p0, 1, 16);
            p1 += __shfl_xor(p1, 1, 16);
            p0 += __shfl_xor(p0, 2, 16);
            p1 += __shfl_xor(p1, 2, 16);
            p0 += __shfl_xor(p0, 4, 16);
            p1 += __shfl_xor(p1, 4, 16);
            p0 += __shfl_xor(p0, 8, 16);
            p1 += __shfl_xor(p1, 8, 16);
            const float w0 = __expf(p0);
            const float w1 = __expf(p1);
            s += w0 + w1;
            acc.x = fmaf(w0, l01a.x, acc.x); acc.x = fmaf(w1, l01b.x, acc.x);
            acc.y = fmaf(w0, l01a.y, acc.y); acc.y = fmaf(w1, l01b.y, acc.y);
            acc.z = fmaf(w0, l23a.x, acc.z); acc.z = fmaf(w1, l23b.x, acc.z);
            acc.w = fmaf(w0, l23a.y, acc.w); acc.w = fmaf(w1, l23b.y, acc.w);
        }
        for (; tt < dg; tt += 4) {
            const int j = sedge[base + tt];
            const uint2 xu = reinterpret_cast<const uint2*>(xl + (size_t)j * 64)[gl];
            const float2 l01 = __half22float2(*reinterpret_cast<const __half2*>(&xu.x));
            const float2 l23 = __half22float2(*reinterpret_cast<const __half2*>(&xu.y));
            float v0 = l01.x + r01.x; v0 = fmaxf(v0, NEG_SLOPE * v0);
            float v1 = l01.y + r01.y; v1 = fmaxf(v1, NEG_SLOPE * v1);
            float v2 = l23.x + r23.x; v2 = fmaxf(v2, NEG_SLOPE * v2);
            float v3 = l23.y + r23.y; v3 = fmaxf(v3, NEG_SLOPE * v3);
            float p = a.x * v0 + a.y * v1 + a.z * v2 + a.w * v3;
            p += __shfl_xor(p, 1, 16);
            p += __shfl_xor(p, 2, 16);
            p += __shfl_xor(p, 4, 16);
            p += __shfl_xor(p, 8, 16);
            const float w = __expf(p);
            s += w;
            acc.x = fmaf(w, l01.x, acc.x);
            acc.y = fmaf(w, l01.y, acc.y);
            acc.z = fmaf(w, l23.x, acc.z);
            acc.w = fmaf(w, l23.y, acc.w);
        }
        s += __shfl_xor(s, 16); s += __shfl_xor(s, 32);
        acc.x += __shfl_xor(acc.x, 16); acc.x += __shfl_xor(acc.x, 32);
        acc.y += __shfl_xor(acc.y, 16); acc.y += __shfl_xor(acc.y, 32);
        acc.z += __shfl_xor(acc.z, 16); acc.z += __shfl_xor(acc.z, 32);
        acc.w += __shfl_xor(acc.w, 16); acc.w += __shfl_xor(acc.w, 32);
        if (q == 0) {
            const float inv = 1.f / s;
            float4 o;
            o.x = fmaf(acc.x, inv, b.x);
            o.y = fmaf(acc.y, inv, b.y);
            o.z = fmaf(acc.z, inv, b.z);
            o.w = fmaf(acc.w, inv, b.w);
            reinterpret_cast<float4*>(out)[(size_t)i * 16 + gl] = o;
        }
    }
}

extern "C" void kernel_launch(void* const* d_in, const int* in_sizes, int n_in,
                              void* d_out, int out_size, void* d_ws, size_t ws_size,
                              hipStream_t stream) {
    const float* x    = (const float*)d_in[0];
    const int*   ei   = (const int*)d_in[1];   // [2,E] (int32 view)
    const float* Wl   = (const float*)d_in[2];
    const float* Wr   = (const float*)d_in[3];
    const float* att  = (const float*)d_in[4];
    const float* bias = (const float*)d_in[5];
    float* out = (float*)d_out;

    const int N = in_sizes[0] / 64;
    const int E = in_sizes[1] / 2;
    const int M = E + N;
    const int ng  = (N + 127) / 128;        // gemm tiles (782)
    const int nch = (M + CH - 1) / CH;      // partition chunks (416)
    const int NB  = (N + BW - 1) / BW;      // buckets (196)

    // workspace: xl[N*64] h | xr[N*64] h | deg[N] | off[N] | bcount[NB]
    //          | part[NB*CAP2] | sedge[NB*CAP2]
    __half* xl = (__half*)d_ws;
    __half* xr = xl + (size_t)N * 64;
    int* deg    = (int*)(xr + (size_t)N * 64);
    int* off    = deg + N;
    int* bcount = off + N;
    int* part   = bcount + NB;
    int* sedge  = part + (size_t)NB * CAP2;

    hipMemsetAsync(bcount, 0, (size_t)NB * sizeof(int), stream);
    k_gp<<<ng + nch, 256, 0, stream>>>(x, Wl, Wr, xl, xr, ei, ei + E,
                                       bcount, part, E, M, NB, ng, N);
    k_bsf<<<NB * 4, 256, 0, stream>>>(part, bcount, sedge, off, deg, N);
    k_fused<<<2048, 256, 0, stream>>>(off, deg, sedge, xl, xr, att, bias, out, N);
}